// Round 2
// baseline (816.079 us; speedup 1.0000x reference)
//
#include <hip/hip_runtime.h>

// Problem constants (IcoUpSampleMaxIndexLayer)
#define NB    16      // batch
#define CIN   256
#define COUT  128
#define VRAW  10242
#define NVERT 40962
#define NPAIR (VRAW * 7)   // 71694 inverted-index entries
#define CAP   16           // bucket capacity per target (Poisson lambda=1.75)
#define LDV   132          // LDS row stride (elements) for x tile: kills q-periodicity

typedef __attribute__((ext_vector_type(8))) short short8;
typedef __attribute__((ext_vector_type(4))) short short4v;
typedef __attribute__((ext_vector_type(4))) float floatx4;

__device__ inline unsigned short f2bf(float f) {
    unsigned u = __builtin_bit_cast(unsigned, f);
    u += 0x7fffu + ((u >> 16) & 1u);   // RNE
    return (unsigned short)(u >> 16);
}

// ---- Kernel 0: convert W (128x256 fp32) to bf16 in ws ----
__global__ __launch_bounds__(256) void convw_kernel(const float* __restrict__ W,
                                                    unsigned short* __restrict__ Wbf) {
    int i = blockIdx.x * 256 + threadIdx.x;   // 32768 elements
    Wbf[i] = f2bf(W[i]);
}

// ---- Kernel 1: build inverted index: for each target t, list of (v,k) with
//      up[down[v]*7+k] == t. buckets layout [slot][t] for coalesced reads. ----
__global__ __launch_bounds__(256) void build_kernel(const int* __restrict__ up,
                                                    const int* __restrict__ down,
                                                    int* __restrict__ cnt,
                                                    unsigned* __restrict__ buckets) {
    int i = blockIdx.x * 256 + threadIdx.x;
    if (i >= NPAIR) return;
    int v = i / 7;
    int k = i - v * 7;
    int t = up[down[v] * 7 + k];
    int pos = atomicAdd(&cnt[t], 1);
    if (pos < CAP) buckets[(size_t)pos * NVERT + t] = ((unsigned)v << 3) | (unsigned)k;
}

// ---- Kernel 2: h[b,o,v] = sum_c W[o,c] x[b,c,v] + bias[o], bf16 MFMA ----
// grid (ceil(VRAW/128), NB), block 256 (4 waves). Wave: 128 o x 32 v.
// x tile (32c x 128v) staged via LDS with coalesced float2 reads.
__global__ __launch_bounds__(256) void gemm_kernel(const float* __restrict__ x,
                                                   const unsigned short* __restrict__ Wbf,
                                                   const float* __restrict__ bias,
                                                   float* __restrict__ h) {
    __shared__ unsigned short xs[32 * LDV];   // [c][v], stride 132 -> 4-way max on frag reads
    const int b    = blockIdx.y;
    const int v0   = blockIdx.x * 128;
    const int tid  = threadIdx.x;
    const int wave = tid >> 6;
    const int lane = tid & 63;
    const int mn   = lane & 15;   // A-row (o) / B-col (v) within 16-tile
    const int q    = lane >> 4;   // quad: k-offset q*8; C/D row-offset q*4
    const int vw   = wave * 32;   // wave's local v base

    const int sc = tid >> 4;            // staging c (0..15, +16 on pass 1)
    const int sv = (tid & 15) * 8;      // staging v segment (8 floats)
    const bool fullTile = (v0 + 128 <= VRAW);

    floatx4 acc[8][2];
#pragma unroll
    for (int ot = 0; ot < 8; ot++) { acc[ot][0] = (floatx4)0.f; acc[ot][1] = (floatx4)0.f; }

    for (int ck = 0; ck < 8; ck++) {
        const int c0 = ck * 32;
        __syncthreads();   // readers of previous tile done
#pragma unroll
        for (int p = 0; p < 2; p++) {
            const int c = p * 16 + sc;
            const float* src = x + ((size_t)(b * CIN + c0 + c)) * VRAW + v0 + sv;
            float f[8];
            if (fullTile) {
#pragma unroll
                for (int u = 0; u < 4; u++) {
                    float2 tt = *(const float2*)(src + 2 * u);
                    f[2 * u] = tt.x; f[2 * u + 1] = tt.y;
                }
            } else {
#pragma unroll
                for (int u = 0; u < 8; u++) {
                    int v = v0 + sv + u;
                    f[u] = (v < VRAW) ? src[u] : 0.f;
                }
            }
            short4v lo, hi;
#pragma unroll
            for (int u = 0; u < 4; u++) { lo[u] = (short)f2bf(f[u]); hi[u] = (short)f2bf(f[4 + u]); }
            unsigned short* dst = &xs[c * LDV + sv];
            *(short4v*)dst = lo;           // 8B stores, 8B-aligned (LDV*2 % 8 == 0)
            *(short4v*)(dst + 4) = hi;
        }
        __syncthreads();

        short8 bfrag[2];
#pragma unroll
        for (int vt = 0; vt < 2; vt++) {
            const int vloc = vw + vt * 16 + mn;
#pragma unroll
            for (int j = 0; j < 8; j++)
                bfrag[vt][j] = (short)xs[(q * 8 + j) * LDV + vloc];
        }
#pragma unroll
        for (int ot = 0; ot < 8; ot++) {
            short8 afrag = *(const short8*)(Wbf + (ot * 16 + mn) * CIN + c0 + q * 8);
            acc[ot][0] = __builtin_amdgcn_mfma_f32_16x16x32_bf16(afrag, bfrag[0], acc[ot][0], 0, 0, 0);
            acc[ot][1] = __builtin_amdgcn_mfma_f32_16x16x32_bf16(afrag, bfrag[1], acc[ot][1], 0, 0, 0);
        }
    }

#pragma unroll
    for (int ot = 0; ot < 8; ot++) {
#pragma unroll
        for (int vt = 0; vt < 2; vt++) {
            const int v = v0 + vw + vt * 16 + mn;
            if (v < VRAW) {
#pragma unroll
                for (int r = 0; r < 4; r++) {
                    const int o = ot * 16 + q * 4 + r;   // C/D: row = quad*4 + reg
                    h[((size_t)b * COUT + o) * VRAW + v] = acc[ot][vt][r] + bias[o];
                }
            }
        }
    }
}

// ---- Kernel 3: gather. One block per (b,o) row. mpi row + h row cached in
// LDS (coalesced global reads); each thread resolves targets by scanning the
// inverted index: winner = max v with mpi[r][v]==k (last-write-wins). ----
__global__ __launch_bounds__(1024) void gather_kernel(const int* __restrict__ cnt,
                                                      const unsigned* __restrict__ buckets,
                                                      const int* __restrict__ mpi,
                                                      const float* __restrict__ h,
                                                      float* __restrict__ y) {
    __shared__ unsigned short mpis[VRAW];   // 20484 B
    __shared__ float hs[VRAW];              // 40968 B (total 61452 < 64K)
    const int r   = blockIdx.x;             // 0..NB*COUT-1
    const int tid = threadIdx.x;

    const int*   mpiRow = mpi + (size_t)r * VRAW;
    const float* hRow   = h   + (size_t)r * VRAW;
    for (int i = tid; i < VRAW; i += 1024) {
        mpis[i] = (unsigned short)mpiRow[i];
        hs[i]   = hRow[i];
    }
    __syncthreads();

    float* yRow = y + (size_t)r * NVERT;
    for (int t = tid; t < NVERT; t += 1024) {
        int n = cnt[t];
        if (n > CAP) n = CAP;
        int best = -1;
        for (int j = 0; j < n; j++) {
            const unsigned e = buckets[(size_t)j * NVERT + t];
            const int v = (int)(e >> 3);
            const int k = (int)(e & 7u);
            if ((int)mpis[v] == k && v > best) best = v;
        }
        yRow[t] = (best >= 0) ? hs[best] : 0.0f;
    }
}

extern "C" void kernel_launch(void* const* d_in, const int* in_sizes, int n_in,
                              void* d_out, int out_size, void* d_ws, size_t ws_size,
                              hipStream_t stream) {
    const float* x    = (const float*)d_in[0];
    const float* W    = (const float*)d_in[1];
    const float* bias = (const float*)d_in[2];
    const int*   up   = (const int*)d_in[3];   // (NVERT, 7)
    const int*   down = (const int*)d_in[4];   // (VRAW,)
    const int*   mpi  = (const int*)d_in[5];   // (NB, COUT, VRAW)
    float* y = (float*)d_out;

    // ws layout:
    //   [0, 64K)                Wbf   (bf16 W, 32768 u16)
    //   [64K, +163848)          cnt   (NVERT ints)
    //   [+163904, +2621568)     buckets (CAP x NVERT u32)
    //   [..., +83902464)        h     (NB*COUT*VRAW fp32)   total ~86.8 MB
    char* ws = (char*)d_ws;
    unsigned short* Wbf = (unsigned short*)ws;
    int*      cnt     = (int*)(ws + 65536);
    unsigned* buckets = (unsigned*)(ws + 65536 + 163904);
    float*    h       = (float*)(ws + 65536 + 163904 + (size_t)CAP * NVERT * 4);

    convw_kernel<<<COUT * CIN / 256, 256, 0, stream>>>(W, Wbf);

    hipMemsetAsync(cnt, 0, NVERT * sizeof(int), stream);
    build_kernel<<<(NPAIR + 255) / 256, 256, 0, stream>>>(up, down, cnt, buckets);

    dim3 ggrid((VRAW + 127) / 128, NB);
    gemm_kernel<<<ggrid, 256, 0, stream>>>(x, Wbf, bias, h);

    gather_kernel<<<NB * COUT, 1024, 0, stream>>>(cnt, buckets, mpi, h, y);
}